// Round 1
// baseline (649.844 us; speedup 1.0000x reference)
//
#include <hip/hip_runtime.h>

#define GG 16384          // G*G = 128*128
#define NBAG 16
#define NPPB 4096         // points per bag
#define NPT (NBAG * NPPB) // 65536 points
#define NCELL (NBAG * GG) // 262144 cells
#define CIN 128
#define CHID 128
#define MAXM NPT          // worst-case occupied cells

// ---------------- occupancy counting ----------------
__global__ __launch_bounds__(256) void k_count(const int* __restrict__ coords,
                                               int* __restrict__ counts) {
  int p = blockIdx.x * 256 + threadIdx.x;
  if (p >= NPT) return;
  int b = p >> 12;
  int q0 = coords[p * 2 + 0] >> 5;   // floor(c/32), coords in [0,4096)
  int q1 = coords[p * 2 + 1] >> 5;
  atomicAdd(&counts[b * GG + q0 * 128 + q1], 1);
}

// per-1024-cell block occupied count
__global__ __launch_bounds__(256) void k_s1(const int* __restrict__ counts,
                                            int* __restrict__ blockcnt) {
  __shared__ int red[256];
  int t = threadIdx.x;
  int base = blockIdx.x * 1024 + t * 4;
  int c = 0;
#pragma unroll
  for (int i = 0; i < 4; ++i) c += (counts[base + i] > 0) ? 1 : 0;
  red[t] = c;
  __syncthreads();
  for (int d = 128; d > 0; d >>= 1) {
    if (t < d) red[t] += red[t + d];
    __syncthreads();
  }
  if (t == 0) blockcnt[blockIdx.x] = red[0];
}

// scan of 256 block counts -> offsets, total M, per-bag occupied counts
__global__ __launch_bounds__(256) void k_s2(const int* __restrict__ blockcnt,
                                            int* __restrict__ blockoff,
                                            int* __restrict__ dM,
                                            int* __restrict__ npts) {
  __shared__ int s[256];
  int t = threadIdx.x;
  int v = blockcnt[t];
  s[t] = v;
  __syncthreads();
  for (int d = 1; d < 256; d <<= 1) {
    int x = (t >= d) ? s[t - d] : 0;
    __syncthreads();
    s[t] += x;
    __syncthreads();
  }
  blockoff[t] = s[t] - v;
  if (t == 255) *dM = s[255];
  if (t < NBAG) {
    int sum = 0;
    for (int i = 0; i < 16; ++i) sum += blockcnt[t * 16 + i];
    npts[t] = sum;
  }
}

// write compact indices (deterministic)
__global__ __launch_bounds__(256) void k_s3(const int* __restrict__ counts,
                                            const int* __restrict__ blockoff,
                                            int* __restrict__ cellidx,
                                            int* __restrict__ cell_of_idx) {
  __shared__ int s[256];
  int t = threadIdx.x;
  int base = blockIdx.x * 1024 + t * 4;
  int occ[4];
  int c = 0;
#pragma unroll
  for (int i = 0; i < 4; ++i) {
    occ[i] = counts[base + i] > 0;
    c += occ[i];
  }
  s[t] = c;
  __syncthreads();
  for (int d = 1; d < 256; d <<= 1) {
    int x = (t >= d) ? s[t - d] : 0;
    __syncthreads();
    s[t] += x;
    __syncthreads();
  }
  int pos = blockoff[blockIdx.x] + s[t] - c;
#pragma unroll
  for (int i = 0; i < 4; ++i) {
    if (occ[i]) {
      cellidx[base + i] = pos;
      cell_of_idx[pos] = base + i;
      pos++;
    } else {
      cellidx[base + i] = -1;
    }
  }
}

// scatter-add point features into compact rows
__global__ __launch_bounds__(256) void k_scatter(const float* __restrict__ x,
                                                 const int* __restrict__ coords,
                                                 const int* __restrict__ cellidx,
                                                 float* __restrict__ feat0) {
  int gid = blockIdx.x * 256 + threadIdx.x;
  int p = gid >> 7, c = gid & 127;
  int b = p >> 12;
  int q0 = coords[p * 2 + 0] >> 5;
  int q1 = coords[p * 2 + 1] >> 5;
  int idx = cellidx[b * GG + q0 * 128 + q1];
  atomicAdd(&feat0[(size_t)idx * CIN + c], x[(size_t)p * CIN + c]);
}

// divide sums by point count
__global__ __launch_bounds__(256) void k_avg(float* __restrict__ feat0,
                                             const int* __restrict__ counts,
                                             const int* __restrict__ cell_of_idx,
                                             const int* __restrict__ dM) {
  int gid = blockIdx.x * 256 + threadIdx.x;
  int cell = gid >> 5, c4 = gid & 31;
  if (cell >= *dM) return;
  float inv = 1.0f / (float)counts[cell_of_idx[cell]];
  float4* p = (float4*)feat0 + (size_t)cell * 32 + c4;
  float4 v = *p;
  v.x *= inv; v.y *= inv; v.z *= inv; v.w *= inv;
  *p = v;
}

// 9-neighbor compact-index table
__global__ __launch_bounds__(256) void k_nbr(const int* __restrict__ cellidx,
                                             const int* __restrict__ cell_of_idx,
                                             const int* __restrict__ dM,
                                             int* __restrict__ nbr) {
  int idx = blockIdx.x * 256 + threadIdx.x;
  if (idx >= *dM) return;
  int cell = cell_of_idx[idx];
  int b = cell >> 14, ij = cell & 16383;
  int i = ij >> 7, j = ij & 127;
#pragma unroll
  for (int dh = 0; dh < 3; ++dh)
#pragma unroll
    for (int dw = 0; dw < 3; ++dw) {
      int ni = i + dh - 1, nj = j + dw - 1;
      int v = -1;
      if (ni >= 0 && ni < 128 && nj >= 0 && nj < 128)
        v = cellidx[b * GG + ni * 128 + nj];
      nbr[idx * 9 + dh * 3 + dw] = v;
    }
}

// gathered sparse conv: 64 cells/block, 256 threads, 4 cells x 8 couts per thread
template <bool POOL>
__global__ __launch_bounds__(256) void k_conv(const float* __restrict__ fin,
                                              const float* __restrict__ W,
                                              float* __restrict__ fout,
                                              float* __restrict__ pooled,
                                              const int* __restrict__ nbr,
                                              const int* __restrict__ cell_of_idx,
                                              const int* __restrict__ dM) {
  __shared__ float As[64][132];  // +4 pad breaks bank aliasing
  __shared__ int sBag[64];
  const int M = *dM;
  const int base = blockIdx.x * 64;
  if (base >= M) return;
  const int t = threadIdx.x;
  const int cg = t >> 4;  // 0..15 -> cells cg*4..cg*4+3
  const int og = t & 15;  // couts og*8..og*8+7
  float acc[4][8];
#pragma unroll
  for (int m = 0; m < 4; ++m)
#pragma unroll
    for (int j = 0; j < 8; ++j) acc[m][j] = 0.f;

  for (int k = 0; k < 9; ++k) {
    __syncthreads();
#pragma unroll
    for (int i = 0; i < 8; ++i) {
      int id = t + 256 * i;
      int r = id >> 5, c4 = id & 31;
      float4 v = make_float4(0.f, 0.f, 0.f, 0.f);
      int cell = base + r;
      if (cell < M) {
        int nb = nbr[cell * 9 + k];
        if (nb >= 0) v = ((const float4*)fin)[(size_t)nb * 32 + c4];
      }
      *(float4*)&As[r][c4 * 4] = v;
    }
    __syncthreads();
    const float* Wk = W + k * 16384;
#pragma unroll 2
    for (int ci = 0; ci < 128; ci += 4) {
      float4 a[4];
#pragma unroll
      for (int m = 0; m < 4; ++m) a[m] = *(const float4*)&As[cg * 4 + m][ci];
#pragma unroll
      for (int s = 0; s < 4; ++s) {
        float4 w0 = *(const float4*)(Wk + (size_t)(ci + s) * 128 + og * 8);
        float4 w1 = *(const float4*)(Wk + (size_t)(ci + s) * 128 + og * 8 + 4);
#pragma unroll
        for (int m = 0; m < 4; ++m) {
          float av = (s == 0) ? a[m].x : (s == 1) ? a[m].y : (s == 2) ? a[m].z : a[m].w;
          acc[m][0] += av * w0.x; acc[m][1] += av * w0.y;
          acc[m][2] += av * w0.z; acc[m][3] += av * w0.w;
          acc[m][4] += av * w1.x; acc[m][5] += av * w1.y;
          acc[m][6] += av * w1.z; acc[m][7] += av * w1.w;
        }
      }
    }
  }

  if (!POOL) {
#pragma unroll
    for (int m = 0; m < 4; ++m) {
      int cell = base + cg * 4 + m;
      if (cell < M) {
        float4 o0 = make_float4(fmaxf(acc[m][0], 0.f), fmaxf(acc[m][1], 0.f),
                                fmaxf(acc[m][2], 0.f), fmaxf(acc[m][3], 0.f));
        float4 o1 = make_float4(fmaxf(acc[m][4], 0.f), fmaxf(acc[m][5], 0.f),
                                fmaxf(acc[m][6], 0.f), fmaxf(acc[m][7], 0.f));
        float4* dst = (float4*)fout + (size_t)cell * 32 + og * 2;
        dst[0] = o0;
        dst[1] = o1;
      }
    }
  } else {
    __syncthreads();
#pragma unroll
    for (int m = 0; m < 4; ++m) {
      int r = cg * 4 + m;
#pragma unroll
      for (int j = 0; j < 8; ++j) As[r][og * 8 + j] = fmaxf(acc[m][j], 0.f);
    }
    if (t < 64) {
      int cell = base + t;
      sBag[t] = (cell < M) ? (cell_of_idx[cell] >> 14) : -1;
    }
    __syncthreads();
    int half = t >> 7, co = t & 127;
    float s = 0.f;
    int cur = -1;
    for (int r = half * 32; r < half * 32 + 32; ++r) {
      int bg = sBag[r];
      if (bg != cur) {
        if (cur >= 0) atomicAdd(&pooled[cur * 128 + co], s);
        cur = bg;
        s = 0.f;
      }
      if (bg >= 0) s += As[r][co];
    }
    if (cur >= 0) atomicAdd(&pooled[cur * 128 + co], s);
  }
}

__global__ __launch_bounds__(256) void k_logits(const float* __restrict__ pooled,
                                                const int* __restrict__ npts,
                                                const float* __restrict__ Wc,
                                                const float* __restrict__ bc,
                                                float* __restrict__ out) {
  int t = threadIdx.x;
  if (t >= 160) return;
  int b = t / 10, n = t % 10;
  float inv = 1.0f / (float)npts[b];
  float s = 0.f;
  for (int c = 0; c < 128; ++c) s += pooled[b * 128 + c] * Wc[c * 10 + n];
  out[t] = s * inv + bc[n];
}

extern "C" void kernel_launch(void* const* d_in, const int* in_sizes, int n_in,
                              void* d_out, int out_size, void* d_ws, size_t ws_size,
                              hipStream_t stream) {
  const float* x = (const float*)d_in[0];
  const int* coords = (const int*)d_in[1];
  const float* W1 = (const float*)d_in[2];
  const float* W2 = (const float*)d_in[3];
  const float* Wc = (const float*)d_in[4];
  const float* bc = (const float*)d_in[5];
  float* out = (float*)d_out;

  char* ws = (char*)d_ws;
  size_t off = 0;
  auto take = [&](size_t bytes) {
    void* p = ws + off;
    off += (bytes + 255) & ~(size_t)255;
    return p;
  };
  int* counts      = (int*)take((size_t)NCELL * 4);
  int* cellidx     = (int*)take((size_t)NCELL * 4);
  int* cell_of_idx = (int*)take((size_t)MAXM * 4);
  int* blockcnt    = (int*)take(256 * 4);
  int* blockoff    = (int*)take(256 * 4);
  int* dM          = (int*)take(4);
  int* npts        = (int*)take(64);
  int* nbr         = (int*)take((size_t)MAXM * 9 * 4);
  float* feat0     = (float*)take((size_t)MAXM * 128 * 4);
  float* feat1     = (float*)take((size_t)MAXM * 128 * 4);
  float* pooled    = (float*)take(16 * 128 * 4);

  hipMemsetAsync(counts, 0, (size_t)NCELL * 4, stream);
  hipMemsetAsync(feat0, 0, (size_t)MAXM * 128 * 4, stream);
  hipMemsetAsync(pooled, 0, 16 * 128 * 4, stream);

  k_count<<<NPT / 256, 256, 0, stream>>>(coords, counts);
  k_s1<<<256, 256, 0, stream>>>(counts, blockcnt);
  k_s2<<<1, 256, 0, stream>>>(blockcnt, blockoff, dM, npts);
  k_s3<<<256, 256, 0, stream>>>(counts, blockoff, cellidx, cell_of_idx);
  k_scatter<<<NPT * 128 / 256, 256, 0, stream>>>(x, coords, cellidx, feat0);
  k_avg<<<MAXM * 32 / 256, 256, 0, stream>>>(feat0, counts, cell_of_idx, dM);
  k_nbr<<<MAXM / 256, 256, 0, stream>>>(cellidx, cell_of_idx, dM, nbr);
  k_conv<false><<<MAXM / 64, 256, 0, stream>>>(feat0, W1, feat1, nullptr, nbr, cell_of_idx, dM);
  k_conv<true><<<MAXM / 64, 256, 0, stream>>>(feat1, W2, nullptr, pooled, nbr, cell_of_idx, dM);
  k_logits<<<1, 256, 0, stream>>>(pooled, npts, Wc, bc, out);
}

// Round 2
// 179.228 us; speedup vs baseline: 3.6258x; 3.6258x over previous
//
#include <hip/hip_runtime.h>
#include <hip/hip_bf16.h>

#define GG 16384          // G*G = 128*128
#define NBAG 16
#define NPT 65536         // total points
#define NCELL (NBAG * GG) // 262144 cells
#define MAXM NPT          // worst-case occupied cells (1024 blocks * 64)

typedef __bf16 bf16x8 __attribute__((ext_vector_type(8)));
typedef float f32x4 __attribute__((ext_vector_type(4)));

// ---------------- occupancy counting ----------------
__global__ __launch_bounds__(256) void k_count(const int* __restrict__ coords,
                                               int* __restrict__ counts) {
  int p = blockIdx.x * 256 + threadIdx.x;
  if (p >= NPT) return;
  int b = p >> 12;
  int q0 = coords[p * 2 + 0] >> 5;
  int q1 = coords[p * 2 + 1] >> 5;
  atomicAdd(&counts[b * GG + q0 * 128 + q1], 1);
}

__global__ __launch_bounds__(256) void k_s1(const int* __restrict__ counts,
                                            int* __restrict__ blockcnt) {
  __shared__ int red[256];
  int t = threadIdx.x;
  int base = blockIdx.x * 1024 + t * 4;
  int c = 0;
#pragma unroll
  for (int i = 0; i < 4; ++i) c += (counts[base + i] > 0) ? 1 : 0;
  red[t] = c;
  __syncthreads();
  for (int d = 128; d > 0; d >>= 1) {
    if (t < d) red[t] += red[t + d];
    __syncthreads();
  }
  if (t == 0) blockcnt[blockIdx.x] = red[0];
}

__global__ __launch_bounds__(256) void k_s2(const int* __restrict__ blockcnt,
                                            int* __restrict__ blockoff,
                                            int* __restrict__ dM,
                                            int* __restrict__ npts) {
  __shared__ int s[256];
  int t = threadIdx.x;
  int v = blockcnt[t];
  s[t] = v;
  __syncthreads();
  for (int d = 1; d < 256; d <<= 1) {
    int x = (t >= d) ? s[t - d] : 0;
    __syncthreads();
    s[t] += x;
    __syncthreads();
  }
  blockoff[t] = s[t] - v;
  if (t == 255) *dM = s[255];
  if (t < NBAG) {
    int sum = 0;
    for (int i = 0; i < 16; ++i) sum += blockcnt[t * 16 + i];
    npts[t] = sum;
  }
}

__global__ __launch_bounds__(256) void k_s3(const int* __restrict__ counts,
                                            const int* __restrict__ blockoff,
                                            int* __restrict__ cellidx,
                                            int* __restrict__ cell_of_idx) {
  __shared__ int s[256];
  int t = threadIdx.x;
  int base = blockIdx.x * 1024 + t * 4;
  int occ[4];
  int c = 0;
#pragma unroll
  for (int i = 0; i < 4; ++i) {
    occ[i] = counts[base + i] > 0;
    c += occ[i];
  }
  s[t] = c;
  __syncthreads();
  for (int d = 1; d < 256; d <<= 1) {
    int x = (t >= d) ? s[t - d] : 0;
    __syncthreads();
    s[t] += x;
    __syncthreads();
  }
  int pos = blockoff[blockIdx.x] + s[t] - c;
#pragma unroll
  for (int i = 0; i < 4; ++i) {
    if (occ[i]) {
      cellidx[base + i] = pos;
      cell_of_idx[pos] = base + i;
      pos++;
    } else {
      cellidx[base + i] = -1;
    }
  }
}

// scatter-add point features into compact fp32 rows
__global__ __launch_bounds__(256) void k_scatter(const float* __restrict__ x,
                                                 const int* __restrict__ coords,
                                                 const int* __restrict__ cellidx,
                                                 float* __restrict__ fsum) {
  int gid = blockIdx.x * 256 + threadIdx.x;
  int p = gid >> 7, c = gid & 127;
  int b = p >> 12;
  int q0 = coords[p * 2 + 0] >> 5;
  int q1 = coords[p * 2 + 1] >> 5;
  int idx = cellidx[b * GG + q0 * 128 + q1];
  atomicAdd(&fsum[(size_t)idx * 128 + c], x[(size_t)p * 128 + c]);
}

// average + convert to bf16
__global__ __launch_bounds__(256) void k_avg(const float* __restrict__ fsum,
                                             const int* __restrict__ counts,
                                             const int* __restrict__ cell_of_idx,
                                             const int* __restrict__ dM,
                                             __hip_bfloat16* __restrict__ feat) {
  int gid = blockIdx.x * 256 + threadIdx.x;
  int cell = gid >> 4, i = gid & 15;
  if (cell >= *dM) return;
  float inv = 1.0f / (float)counts[cell_of_idx[cell]];
  const float4* src = (const float4*)fsum + (size_t)cell * 32 + i * 2;
  float4 v0 = src[0], v1 = src[1];
  __align__(16) __hip_bfloat16 h[8];
  h[0] = __float2bfloat16(v0.x * inv);
  h[1] = __float2bfloat16(v0.y * inv);
  h[2] = __float2bfloat16(v0.z * inv);
  h[3] = __float2bfloat16(v0.w * inv);
  h[4] = __float2bfloat16(v1.x * inv);
  h[5] = __float2bfloat16(v1.y * inv);
  h[6] = __float2bfloat16(v1.z * inv);
  h[7] = __float2bfloat16(v1.w * inv);
  *(int4*)(feat + (size_t)cell * 128 + i * 8) = *(const int4*)h;
}

// weight transpose+cast: W[k][ci][co] fp32 -> Wt[k][co][ci] bf16
__global__ __launch_bounds__(256) void k_wt(const float* __restrict__ W,
                                            __hip_bfloat16* __restrict__ Wt) {
  int id = blockIdx.x * 256 + threadIdx.x;  // 9*128*128
  int k = id >> 14, rem = id & 16383, co = rem >> 7, ci = rem & 127;
  Wt[id] = __float2bfloat16(W[k * 16384 + ci * 128 + co]);
}

// 9-neighbor compact-index table, padded with -1 beyond M
__global__ __launch_bounds__(256) void k_nbr(const int* __restrict__ cellidx,
                                             const int* __restrict__ cell_of_idx,
                                             const int* __restrict__ dM,
                                             int* __restrict__ nbr) {
  int idx = blockIdx.x * 256 + threadIdx.x;
  if (idx >= MAXM) return;
  if (idx >= *dM) {
#pragma unroll
    for (int j = 0; j < 9; ++j) nbr[idx * 9 + j] = -1;
    return;
  }
  int cell = cell_of_idx[idx];
  int b = cell >> 14, ij = cell & 16383;
  int i = ij >> 7, j = ij & 127;
#pragma unroll
  for (int dh = 0; dh < 3; ++dh)
#pragma unroll
    for (int dw = 0; dw < 3; ++dw) {
      int ni = i + dh - 1, nj = j + dw - 1;
      int v = -1;
      if (ni >= 0 && ni < 128 && nj >= 0 && nj < 128)
        v = cellidx[b * GG + ni * 128 + nj];
      nbr[idx * 9 + dh * 3 + dw] = v;
    }
}

// MFMA gathered sparse conv: 64 cells x 128 couts per block, 4 waves.
// Wave w owns rows 0..63 x couts [w*32, w*32+32). K = 9 taps x 128 cin.
// Per-tap A tile (64x128 bf16 = 16KB) double-buffered in LDS, XOR-swizzled
// in 16B chunks (chunk ^= row&7) to kill the stride-256B bank conflict.
template <bool POOL>
__global__ __launch_bounds__(256) void k_conv(
    const __hip_bfloat16* __restrict__ fin,
    const __hip_bfloat16* __restrict__ Wt,   // [9][128co][128ci] bf16
    __hip_bfloat16* __restrict__ fout,
    float* __restrict__ pooled,
    const int* __restrict__ nbr,
    const int* __restrict__ cell_of_idx,
    const int* __restrict__ dM) {
  __shared__ __align__(16) char smem[32768];  // 2x16KB staging; POOL: f32[64][128]
  __shared__ int sBag[64];
  const int M = *dM;
  const int base = blockIdx.x * 64;
  if (base >= M) return;
  const int t = threadIdx.x;
  const int l = t & 63;
  const int w = t >> 6;
  const int srow = t >> 2;  // staging row 0..63
  const int scol = t & 3;   // staging chunk group

  f32x4 acc[4][2];
#pragma unroll
  for (int mf = 0; mf < 4; ++mf)
#pragma unroll
    for (int nf = 0; nf < 2; ++nf) acc[mf][nf] = f32x4{0.f, 0.f, 0.f, 0.f};

  int4 stg[4];
  auto sload = [&](int k) {
    int nb = nbr[(base + srow) * 9 + k];
    const int4* src = (const int4*)(fin + (size_t)nb * 128);
#pragma unroll
    for (int i = 0; i < 4; ++i) {
      stg[i] = (nb >= 0) ? src[4 * scol + i] : make_int4(0, 0, 0, 0);
    }
  };
  auto swrite = [&](char* buf) {
#pragma unroll
    for (int i = 0; i < 4; ++i) {
      int c = (4 * scol + i) ^ (srow & 7);
      *(int4*)(buf + srow * 256 + c * 16) = stg[i];
    }
  };

  sload(0);
  swrite(smem);
  __syncthreads();

  for (int k = 0; k < 9; ++k) {
    if (k < 8) sload(k + 1);  // T14: issue next-tap gather before MFMAs

    const __hip_bfloat16* Wk = Wt + (size_t)k * 16384 + (size_t)(w * 32) * 128;
    const char* cur = smem + (k & 1) * 16384;

    bf16x8 bfr[4][2];
#pragma unroll
    for (int kb = 0; kb < 4; ++kb) {
      bfr[kb][0] = *(const bf16x8*)(Wk + (l & 15) * 128 + kb * 32 + (l >> 4) * 8);
      bfr[kb][1] = *(const bf16x8*)(Wk + (16 + (l & 15)) * 128 + kb * 32 + (l >> 4) * 8);
    }
#pragma unroll
    for (int kb = 0; kb < 4; ++kb) {
#pragma unroll
      for (int mf = 0; mf < 4; ++mf) {
        int row = mf * 16 + (l & 15);
        int ch = (kb * 4 + (l >> 4)) ^ (l & 7);
        bf16x8 a = *(const bf16x8*)(cur + row * 256 + ch * 16);
        acc[mf][0] = __builtin_amdgcn_mfma_f32_16x16x32_bf16(a, bfr[kb][0], acc[mf][0], 0, 0, 0);
        acc[mf][1] = __builtin_amdgcn_mfma_f32_16x16x32_bf16(a, bfr[kb][1], acc[mf][1], 0, 0, 0);
      }
    }

    if (k < 8) swrite(smem + ((k + 1) & 1) * 16384);
    __syncthreads();
  }

  if (!POOL) {
    // acc -> bf16 -> swizzled LDS -> coalesced b128 global stores
#pragma unroll
    for (int mf = 0; mf < 4; ++mf)
#pragma unroll
      for (int nf = 0; nf < 2; ++nf)
#pragma unroll
        for (int r = 0; r < 4; ++r) {
          int row = mf * 16 + (l >> 4) * 4 + r;
          int col = w * 32 + nf * 16 + (l & 15);
          int off = (col * 2) ^ ((row & 7) << 4);
          *(__hip_bfloat16*)(smem + row * 256 + off) =
              __float2bfloat16(fmaxf(acc[mf][nf][r], 0.f));
        }
    __syncthreads();
#pragma unroll
    for (int i = 0; i < 4; ++i) {
      int c = 4 * scol + i;
      int4 v = *(const int4*)(smem + srow * 256 + (c ^ (srow & 7)) * 16);
      *(int4*)((char*)fout + (size_t)(base + srow) * 256 + c * 16) = v;
    }
  } else {
    float* Ps = (float*)smem;  // [64][128] fp32
#pragma unroll
    for (int mf = 0; mf < 4; ++mf)
#pragma unroll
      for (int nf = 0; nf < 2; ++nf)
#pragma unroll
        for (int r = 0; r < 4; ++r) {
          int row = mf * 16 + (l >> 4) * 4 + r;
          int col = w * 32 + nf * 16 + (l & 15);
          Ps[row * 128 + col] = fmaxf(acc[mf][nf][r], 0.f);
        }
    if (t < 64) {
      int cell = base + t;
      sBag[t] = (cell < M) ? (cell_of_idx[cell] >> 14) : -1;
    }
    __syncthreads();
    int half = t >> 7, co = t & 127;
    float s = 0.f;
    int curb = -1;
    for (int r = half * 32; r < half * 32 + 32; ++r) {
      int bg = sBag[r];
      if (bg != curb) {
        if (curb >= 0) atomicAdd(&pooled[curb * 128 + co], s);
        curb = bg;
        s = 0.f;
      }
      if (bg >= 0) s += Ps[r * 128 + co];
    }
    if (curb >= 0) atomicAdd(&pooled[curb * 128 + co], s);
  }
}

__global__ __launch_bounds__(256) void k_logits(const float* __restrict__ pooled,
                                                const int* __restrict__ npts,
                                                const float* __restrict__ Wc,
                                                const float* __restrict__ bc,
                                                float* __restrict__ out) {
  int t = threadIdx.x;
  if (t >= 160) return;
  int b = t / 10, n = t % 10;
  float inv = 1.0f / (float)npts[b];
  float s = 0.f;
  for (int c = 0; c < 128; ++c) s += pooled[b * 128 + c] * Wc[c * 10 + n];
  out[t] = s * inv + bc[n];
}

extern "C" void kernel_launch(void* const* d_in, const int* in_sizes, int n_in,
                              void* d_out, int out_size, void* d_ws, size_t ws_size,
                              hipStream_t stream) {
  const float* x = (const float*)d_in[0];
  const int* coords = (const int*)d_in[1];
  const float* W1 = (const float*)d_in[2];
  const float* W2 = (const float*)d_in[3];
  const float* Wc = (const float*)d_in[4];
  const float* bc = (const float*)d_in[5];
  float* out = (float*)d_out;

  char* ws = (char*)d_ws;
  size_t off = 0;
  auto take = [&](size_t bytes) {
    void* p = ws + off;
    off += (bytes + 255) & ~(size_t)255;
    return p;
  };
  int* counts      = (int*)take((size_t)NCELL * 4);
  int* cellidx     = (int*)take((size_t)NCELL * 4);
  int* cell_of_idx = (int*)take((size_t)MAXM * 4);
  int* blockcnt    = (int*)take(256 * 4);
  int* blockoff    = (int*)take(256 * 4);
  int* dM          = (int*)take(4);
  int* npts        = (int*)take(64);
  int* nbr         = (int*)take((size_t)MAXM * 9 * 4);
  float* fsum      = (float*)take((size_t)MAXM * 128 * 4);
  __hip_bfloat16* feat0 = (__hip_bfloat16*)take((size_t)MAXM * 128 * 2);
  __hip_bfloat16* feat1 = (__hip_bfloat16*)take((size_t)MAXM * 128 * 2);
  __hip_bfloat16* Wt1   = (__hip_bfloat16*)take((size_t)9 * 128 * 128 * 2);
  __hip_bfloat16* Wt2   = (__hip_bfloat16*)take((size_t)9 * 128 * 128 * 2);
  float* pooled    = (float*)take(16 * 128 * 4);

  hipMemsetAsync(counts, 0, (size_t)NCELL * 4, stream);
  hipMemsetAsync(fsum, 0, (size_t)MAXM * 128 * 4, stream);
  hipMemsetAsync(pooled, 0, 16 * 128 * 4, stream);

  k_wt<<<576, 256, 0, stream>>>(W1, Wt1);
  k_wt<<<576, 256, 0, stream>>>(W2, Wt2);
  k_count<<<NPT / 256, 256, 0, stream>>>(coords, counts);
  k_s1<<<256, 256, 0, stream>>>(counts, blockcnt);
  k_s2<<<1, 256, 0, stream>>>(blockcnt, blockoff, dM, npts);
  k_s3<<<256, 256, 0, stream>>>(counts, blockoff, cellidx, cell_of_idx);
  k_scatter<<<NPT * 128 / 256, 256, 0, stream>>>(x, coords, cellidx, fsum);
  k_avg<<<MAXM * 16 / 256, 256, 0, stream>>>(fsum, counts, cell_of_idx, dM, feat0);
  k_nbr<<<MAXM / 256, 256, 0, stream>>>(cellidx, cell_of_idx, dM, nbr);
  k_conv<false><<<MAXM / 64, 256, 0, stream>>>(feat0, Wt1, feat1, nullptr, nbr, cell_of_idx, dM);
  k_conv<true><<<MAXM / 64, 256, 0, stream>>>(feat1, Wt2, nullptr, pooled, nbr, cell_of_idx, dM);
  k_logits<<<1, 256, 0, stream>>>(pooled, npts, Wc, bc, out);
}

// Round 3
// 139.216 us; speedup vs baseline: 4.6679x; 1.2874x over previous
//
#include <hip/hip_runtime.h>
#include <hip/hip_bf16.h>

#define GG 16384          // G*G
#define NBAG 16
#define NPT 65536
#define NCELL (NBAG * GG)
#define MAXM NPT
#define ZROW MAXM         // dedicated zero row in feat buffers (sized MAXM+1 rows)

typedef __bf16 bf16x8 __attribute__((ext_vector_type(8)));
typedef float f32x4 __attribute__((ext_vector_type(4)));

// ---------------- occupancy counting ----------------
__global__ __launch_bounds__(256) void k_count(const int* __restrict__ coords,
                                               int* __restrict__ counts) {
  int p = blockIdx.x * 256 + threadIdx.x;
  if (p >= NPT) return;
  int b = p >> 12;
  int q0 = coords[p * 2 + 0] >> 5;
  int q1 = coords[p * 2 + 1] >> 5;
  atomicAdd(&counts[b * GG + q0 * 128 + q1], 1);
}

__global__ __launch_bounds__(256) void k_s1(const int* __restrict__ counts,
                                            int* __restrict__ blockcnt) {
  __shared__ int red[256];
  int t = threadIdx.x;
  int base = blockIdx.x * 1024 + t * 4;
  int c = 0;
#pragma unroll
  for (int i = 0; i < 4; ++i) c += (counts[base + i] > 0) ? 1 : 0;
  red[t] = c;
  __syncthreads();
  for (int d = 128; d > 0; d >>= 1) {
    if (t < d) red[t] += red[t + d];
    __syncthreads();
  }
  if (t == 0) blockcnt[blockIdx.x] = red[0];
}

__global__ __launch_bounds__(256) void k_s2(const int* __restrict__ blockcnt,
                                            int* __restrict__ blockoff,
                                            int* __restrict__ dM,
                                            int* __restrict__ npts) {
  __shared__ int s[256];
  int t = threadIdx.x;
  int v = blockcnt[t];
  s[t] = v;
  __syncthreads();
  for (int d = 1; d < 256; d <<= 1) {
    int x = (t >= d) ? s[t - d] : 0;
    __syncthreads();
    s[t] += x;
    __syncthreads();
  }
  blockoff[t] = s[t] - v;
  if (t == 255) *dM = s[255];
  if (t < NBAG) {
    int sum = 0;
    for (int i = 0; i < 16; ++i) sum += blockcnt[t * 16 + i];
    npts[t] = sum;
  }
}

__global__ __launch_bounds__(256) void k_s3(const int* __restrict__ counts,
                                            const int* __restrict__ blockoff,
                                            int* __restrict__ cellidx,
                                            int* __restrict__ cell_of_idx) {
  __shared__ int s[256];
  int t = threadIdx.x;
  int base = blockIdx.x * 1024 + t * 4;
  int occ[4];
  int c = 0;
#pragma unroll
  for (int i = 0; i < 4; ++i) {
    occ[i] = counts[base + i] > 0;
    c += occ[i];
  }
  s[t] = c;
  __syncthreads();
  for (int d = 1; d < 256; d <<= 1) {
    int x = (t >= d) ? s[t - d] : 0;
    __syncthreads();
    s[t] += x;
    __syncthreads();
  }
  int pos = blockoff[blockIdx.x] + s[t] - c;
#pragma unroll
  for (int i = 0; i < 4; ++i) {
    if (occ[i]) {
      cellidx[base + i] = pos;
      cell_of_idx[pos] = base + i;
      pos++;
    } else {
      cellidx[base + i] = -1;
    }
  }
}

__global__ __launch_bounds__(256) void k_scatter(const float* __restrict__ x,
                                                 const int* __restrict__ coords,
                                                 const int* __restrict__ cellidx,
                                                 float* __restrict__ fsum) {
  int gid = blockIdx.x * 256 + threadIdx.x;
  int p = gid >> 7, c = gid & 127;
  int b = p >> 12;
  int q0 = coords[p * 2 + 0] >> 5;
  int q1 = coords[p * 2 + 1] >> 5;
  int idx = cellidx[b * GG + q0 * 128 + q1];
  atomicAdd(&fsum[(size_t)idx * 128 + c], x[(size_t)p * 128 + c]);
}

// average + cast to bf16; also zero the ZROW of feat0 and feat1
__global__ __launch_bounds__(256) void k_avg(const float* __restrict__ fsum,
                                             const int* __restrict__ counts,
                                             const int* __restrict__ cell_of_idx,
                                             const int* __restrict__ dM,
                                             __hip_bfloat16* __restrict__ feat0,
                                             __hip_bfloat16* __restrict__ feat1) {
  int gid = blockIdx.x * 256 + threadIdx.x;
  int cell = gid >> 4, i = gid & 15;
  int M = *dM;
  if (cell >= M) {
    if (cell == M) {            // zero feat0 ZROW (16 threads x 16B = 256B)
      *(int4*)((char*)(feat0 + (size_t)ZROW * 128) + i * 16) = make_int4(0, 0, 0, 0);
    } else if (cell == M + 1) { // zero feat1 ZROW
      *(int4*)((char*)(feat1 + (size_t)ZROW * 128) + i * 16) = make_int4(0, 0, 0, 0);
    }
    return;
  }
  float inv = 1.0f / (float)counts[cell_of_idx[cell]];
  const float4* src = (const float4*)fsum + (size_t)cell * 32 + i * 2;
  float4 v0 = src[0], v1 = src[1];
  __align__(16) __hip_bfloat16 h[8];
  h[0] = __float2bfloat16(v0.x * inv);
  h[1] = __float2bfloat16(v0.y * inv);
  h[2] = __float2bfloat16(v0.z * inv);
  h[3] = __float2bfloat16(v0.w * inv);
  h[4] = __float2bfloat16(v1.x * inv);
  h[5] = __float2bfloat16(v1.y * inv);
  h[6] = __float2bfloat16(v1.z * inv);
  h[7] = __float2bfloat16(v1.w * inv);
  *(int4*)(feat0 + (size_t)cell * 128 + i * 8) = *(const int4*)h;
}

// Weight transpose + cast + chunk pre-swizzle (both convs in one launch).
// Output element layout: Wt[k][co][ chunk'=( (ci>>3) ^ (co&7) ) ][ci&7]
// so that global_load_lds (linear) + swizzled ds_read is bank-conflict-free.
__global__ __launch_bounds__(256) void k_wt(const float* __restrict__ W1,
                                            const float* __restrict__ W2,
                                            __hip_bfloat16* __restrict__ Wt1,
                                            __hip_bfloat16* __restrict__ Wt2) {
  int id = blockIdx.x * 256 + threadIdx.x;  // < 2*147456
  const float* W = (id < 147456) ? W1 : W2;
  __hip_bfloat16* Wt = (id < 147456) ? Wt1 : Wt2;
  int r = (id < 147456) ? id : id - 147456;
  int k = r >> 14, rem = r & 16383, co = rem >> 7, ci = rem & 127;
  int dst = k * 16384 + co * 128 + (((ci >> 3) ^ (co & 7)) << 3) + (ci & 7);
  Wt[dst] = __float2bfloat16(W[k * 16384 + ci * 128 + co]);
}

// transposed 9-neighbor table nbrt[k][idx]; unoccupied/out-of-range -> ZROW
__global__ __launch_bounds__(256) void k_nbr(const int* __restrict__ cellidx,
                                             const int* __restrict__ cell_of_idx,
                                             const int* __restrict__ dM,
                                             int* __restrict__ nbrt) {
  int idx = blockIdx.x * 256 + threadIdx.x;
  if (idx >= MAXM) return;
  if (idx >= *dM) {
#pragma unroll
    for (int j = 0; j < 9; ++j) nbrt[j * MAXM + idx] = ZROW;
    return;
  }
  int cell = cell_of_idx[idx];
  int b = cell >> 14, ij = cell & 16383;
  int i = ij >> 7, j = ij & 127;
#pragma unroll
  for (int dh = 0; dh < 3; ++dh)
#pragma unroll
    for (int dw = 0; dw < 3; ++dw) {
      int ni = i + dh - 1, nj = j + dw - 1;
      int v = -1;
      if (ni >= 0 && ni < 128 && nj >= 0 && nj < 128)
        v = cellidx[b * GG + ni * 128 + nj];
      nbrt[(dh * 3 + dw) * MAXM + idx] = (v < 0) ? ZROW : v;
    }
}

// MFMA gathered sparse conv, barrier-light:
//   block = 4 waves; wave w -> rows [base + w*32, +32), couts [cg*64, +64).
//   A-frags: direct global gather into regs, 1 tap ahead (ZROW => no predication).
//   W: per-tap 16KB tile (pre-swizzled), global_load_lds into 2x16KB LDS dbuf.
//   One barrier per tap; it only waits on the predictable W stream.
template <bool POOL>
__global__ __launch_bounds__(256, 4) void k_conv(
    const __hip_bfloat16* __restrict__ fin,   // [MAXM+1][128]
    const __hip_bfloat16* __restrict__ Wt,    // [9][128][128] pre-swizzled
    __hip_bfloat16* __restrict__ fout,        // conv1 out
    float* __restrict__ pooled,               // conv2 pooled
    const int* __restrict__ nbrt,             // [9][MAXM]
    const int* __restrict__ cell_of_idx,
    const int* __restrict__ dM) {
  __shared__ __align__(16) char smem[32768];
  const int M = *dM;
  const int cg = blockIdx.x & 1;
  const int base = (blockIdx.x >> 1) * 128;
  if (base >= M) return;
  const int t = threadIdx.x;
  const int w = t >> 6;
  const int l = t & 63;
  const int u = l >> 4;  // 0..3
  const int c = l & 15;
  const int wrow = base + w * 32;

  auto stageW = [&](int k, int b) {
    const __hip_bfloat16* gw = Wt + (size_t)k * 16384 + cg * 8192 + w * 2048;
    char* lb = smem + b * 16384 + w * 4096;
#pragma unroll
    for (int j = 0; j < 4; ++j) {
      __builtin_amdgcn_global_load_lds(
          (const __attribute__((address_space(1))) void*)(gw + j * 512 + l * 8),
          (__attribute__((address_space(3))) void*)(lb + j * 1024), 16, 0, 0);
    }
  };
  auto loadA = [&](int nb, int kb) {
    return *(const bf16x8*)((const char*)fin + (size_t)nb * 256 + kb * 64 + u * 16);
  };

  f32x4 acc[2][4];
#pragma unroll
  for (int mf = 0; mf < 2; ++mf)
#pragma unroll
    for (int nf = 0; nf < 4; ++nf) acc[mf][nf] = f32x4{0.f, 0.f, 0.f, 0.f};

  int nb_c[2], nb_n[2];
  nb_c[0] = nbrt[0 * MAXM + wrow + c];
  nb_c[1] = nbrt[0 * MAXM + wrow + 16 + c];
  nb_n[0] = nbrt[1 * MAXM + wrow + c];
  nb_n[1] = nbrt[1 * MAXM + wrow + 16 + c];
  stageW(0, 0);
  bf16x8 aC[2][4], aN[2][4];
#pragma unroll
  for (int mf = 0; mf < 2; ++mf)
#pragma unroll
    for (int kb = 0; kb < 4; ++kb) aC[mf][kb] = loadA(nb_c[mf], kb);
  __syncthreads();  // drains vmcnt: W(0) staged, A(0) in regs

#pragma unroll
  for (int k = 0; k < 9; ++k) {
    if (k < 8) {
      stageW(k + 1, (k + 1) & 1);  // into the other buffer
#pragma unroll
      for (int mf = 0; mf < 2; ++mf)
#pragma unroll
        for (int kb = 0; kb < 4; ++kb) aN[mf][kb] = loadA(nb_n[mf], kb);
    }
    if (k < 7) {  // nbr two taps ahead
      nb_n[0] = nbrt[(k + 2) * MAXM + wrow + c];
      nb_n[1] = nbrt[(k + 2) * MAXM + wrow + 16 + c];
    }
    const char* wb = smem + (k & 1) * 16384;
#pragma unroll
    for (int kb = 0; kb < 4; ++kb) {
      bf16x8 wf[4];
#pragma unroll
      for (int nf = 0; nf < 4; ++nf) {
        int co = nf * 16 + c;
        int ch = (kb * 4 + u) ^ (c & 7);
        wf[nf] = *(const bf16x8*)(wb + co * 256 + ch * 16);
      }
#pragma unroll
      for (int mf = 0; mf < 2; ++mf)
#pragma unroll
        for (int nf = 0; nf < 4; ++nf)
          acc[mf][nf] = __builtin_amdgcn_mfma_f32_16x16x32_bf16(
              aC[mf][kb], wf[nf], acc[mf][nf], 0, 0, 0);
    }
    __syncthreads();  // drains stage W(k+1) + A(k+1); flips buffers
    if (k < 8) {
#pragma unroll
      for (int mf = 0; mf < 2; ++mf)
#pragma unroll
        for (int kb = 0; kb < 4; ++kb) aC[mf][kb] = aN[mf][kb];
    }
  }

  if (!POOL) {
    // acc -> bf16 -> per-wave LDS region (stride 144 breaks conflicts) -> b128 stores
    char* ep = smem + w * 4608;
#pragma unroll
    for (int mf = 0; mf < 2; ++mf)
#pragma unroll
      for (int nf = 0; nf < 4; ++nf)
#pragma unroll
        for (int i = 0; i < 4; ++i) {
          int rl = mf * 16 + u * 4 + i;
          int col = nf * 16 + c;
          *(__hip_bfloat16*)(ep + rl * 144 + col * 2) =
              __float2bfloat16(fmaxf(acc[mf][nf][i], 0.f));
        }
    __syncthreads();
#pragma unroll
    for (int p = 0; p < 4; ++p) {
      int rl = p * 8 + (l >> 3);
      int grow = wrow + rl;
      int4 v = *(const int4*)(ep + rl * 144 + (l & 7) * 16);
      if (grow < M)
        *(int4*)((char*)fout + (size_t)grow * 256 + cg * 128 + (l & 7) * 16) = v;
    }
  } else {
    if (wrow < M) {
      int b0 = cell_of_idx[wrow] >> 14;
      int lastr = min(wrow + 31, M - 1);
      int b1 = cell_of_idx[lastr] >> 14;
      float p0[4] = {0.f, 0.f, 0.f, 0.f}, p1[4] = {0.f, 0.f, 0.f, 0.f};
#pragma unroll
      for (int mf = 0; mf < 2; ++mf)
#pragma unroll
        for (int i = 0; i < 4; ++i) {
          int r = wrow + mf * 16 + u * 4 + i;
          int bg = (r < M) ? (cell_of_idx[r] >> 14) : -1;
#pragma unroll
          for (int nf = 0; nf < 4; ++nf) {
            float v = fmaxf(acc[mf][nf][i], 0.f);
            if (bg == b0) p0[nf] += v;
            else if (bg == b1) p1[nf] += v;
          }
        }
      bool two = (b1 != b0);
#pragma unroll
      for (int nf = 0; nf < 4; ++nf) {
        p0[nf] += __shfl_xor(p0[nf], 16);
        p0[nf] += __shfl_xor(p0[nf], 32);
        p1[nf] += __shfl_xor(p1[nf], 16);
        p1[nf] += __shfl_xor(p1[nf], 32);
      }
      if (u == 0) {
#pragma unroll
        for (int nf = 0; nf < 4; ++nf) {
          atomicAdd(&pooled[b0 * 128 + cg * 64 + nf * 16 + c], p0[nf]);
          if (two) atomicAdd(&pooled[b1 * 128 + cg * 64 + nf * 16 + c], p1[nf]);
        }
      }
    }
  }
}

__global__ __launch_bounds__(256) void k_logits(const float* __restrict__ pooled,
                                                const int* __restrict__ npts,
                                                const float* __restrict__ Wc,
                                                const float* __restrict__ bc,
                                                float* __restrict__ out) {
  int t = threadIdx.x;
  if (t >= 160) return;
  int b = t / 10, n = t % 10;
  float inv = 1.0f / (float)npts[b];
  float s = 0.f;
  for (int c = 0; c < 128; ++c) s += pooled[b * 128 + c] * Wc[c * 10 + n];
  out[t] = s * inv + bc[n];
}

extern "C" void kernel_launch(void* const* d_in, const int* in_sizes, int n_in,
                              void* d_out, int out_size, void* d_ws, size_t ws_size,
                              hipStream_t stream) {
  const float* x = (const float*)d_in[0];
  const int* coords = (const int*)d_in[1];
  const float* W1 = (const float*)d_in[2];
  const float* W2 = (const float*)d_in[3];
  const float* Wc = (const float*)d_in[4];
  const float* bc = (const float*)d_in[5];
  float* out = (float*)d_out;

  char* ws = (char*)d_ws;
  size_t off = 0;
  auto take = [&](size_t bytes) {
    void* p = ws + off;
    off += (bytes + 255) & ~(size_t)255;
    return p;
  };
  int* counts      = (int*)take((size_t)NCELL * 4);
  int* cellidx     = (int*)take((size_t)NCELL * 4);
  int* cell_of_idx = (int*)take((size_t)MAXM * 4);
  int* blockcnt    = (int*)take(256 * 4);
  int* blockoff    = (int*)take(256 * 4);
  int* dM          = (int*)take(4);
  int* npts        = (int*)take(64);
  int* nbrt        = (int*)take((size_t)9 * MAXM * 4);
  float* fsum      = (float*)take((size_t)MAXM * 128 * 4);
  __hip_bfloat16* feat0 = (__hip_bfloat16*)take((size_t)(MAXM + 1) * 128 * 2);
  __hip_bfloat16* feat1 = (__hip_bfloat16*)take((size_t)(MAXM + 1) * 128 * 2);
  __hip_bfloat16* Wt1   = (__hip_bfloat16*)take((size_t)9 * 128 * 128 * 2);
  __hip_bfloat16* Wt2   = (__hip_bfloat16*)take((size_t)9 * 128 * 128 * 2);
  float* pooled    = (float*)take(16 * 128 * 4);

  hipMemsetAsync(counts, 0, (size_t)NCELL * 4, stream);
  hipMemsetAsync(fsum, 0, (size_t)MAXM * 128 * 4, stream);
  hipMemsetAsync(pooled, 0, 16 * 128 * 4, stream);

  k_wt<<<1152, 256, 0, stream>>>(W1, W2, Wt1, Wt2);
  k_count<<<NPT / 256, 256, 0, stream>>>(coords, counts);
  k_s1<<<256, 256, 0, stream>>>(counts, blockcnt);
  k_s2<<<1, 256, 0, stream>>>(blockcnt, blockoff, dM, npts);
  k_s3<<<256, 256, 0, stream>>>(counts, blockoff, cellidx, cell_of_idx);
  k_scatter<<<NPT * 128 / 256, 256, 0, stream>>>(x, coords, cellidx, fsum);
  k_avg<<<((MAXM + 2) * 16 + 255) / 256, 256, 0, stream>>>(fsum, counts, cell_of_idx, dM, feat0, feat1);
  k_nbr<<<MAXM / 256, 256, 0, stream>>>(cellidx, cell_of_idx, dM, nbrt);
  k_conv<false><<<(MAXM / 128) * 2, 256, 0, stream>>>(feat0, Wt1, feat1, nullptr, nbrt, cell_of_idx, dM);
  k_conv<true><<<(MAXM / 128) * 2, 256, 0, stream>>>(feat1, Wt2, nullptr, pooled, nbrt, cell_of_idx, dM);
  k_logits<<<1, 256, 0, stream>>>(pooled, npts, Wc, bc, out);
}

// Round 4
// 134.038 us; speedup vs baseline: 4.8482x; 1.0386x over previous
//
#include <hip/hip_runtime.h>
#include <hip/hip_bf16.h>

#define GG 16384          // G*G
#define NBAG 16
#define NPT 65536
#define NCELL (NBAG * GG)
#define MAXM NPT
#define ZROW MAXM         // dedicated zero row in feat buffers (sized MAXM+1 rows)

typedef __bf16 bf16x8 __attribute__((ext_vector_type(8)));
typedef float f32x4 __attribute__((ext_vector_type(4)));

// fused zero: counts (1MB) + fsum (32MB) + pooled (8KB), one launch, int4 stores
__global__ __launch_bounds__(256) void k_zero(float* __restrict__ fsum,
                                              int* __restrict__ counts,
                                              float* __restrict__ pooled) {
  int tid = blockIdx.x * 256 + threadIdx.x;  // grid 2048*256 = 524288
  int4 z = make_int4(0, 0, 0, 0);
#pragma unroll
  for (int i = 0; i < 4; ++i) ((int4*)fsum)[tid + i * 524288] = z;
  if (tid < 65536) ((int4*)counts)[tid] = z;
  if (tid < 512) ((int4*)pooled)[tid] = z;
}

// fused: weight transpose+cast+pre-swizzle (blocks [0,1152)) and point count
// (blocks [1152,1408)). counts must be zeroed first (k_zero precedes on stream).
__global__ __launch_bounds__(256) void k_setup(const float* __restrict__ W1,
                                               const float* __restrict__ W2,
                                               __hip_bfloat16* __restrict__ Wt1,
                                               __hip_bfloat16* __restrict__ Wt2,
                                               const int* __restrict__ coords,
                                               int* __restrict__ counts) {
  int b = blockIdx.x, t = threadIdx.x;
  if (b < 1152) {
    int id = b * 256 + t;  // < 2*147456
    const float* W = (id < 147456) ? W1 : W2;
    __hip_bfloat16* Wt = (id < 147456) ? Wt1 : Wt2;
    int r = (id < 147456) ? id : id - 147456;
    int k = r >> 14, rem = r & 16383, co = rem >> 7, ci = rem & 127;
    int dst = k * 16384 + co * 128 + (((ci >> 3) ^ (co & 7)) << 3) + (ci & 7);
    Wt[dst] = __float2bfloat16(W[k * 16384 + ci * 128 + co]);
  } else {
    int p = (b - 1152) * 256 + t;
    int bg = p >> 12;
    int q0 = coords[p * 2 + 0] >> 5;
    int q1 = coords[p * 2 + 1] >> 5;
    atomicAdd(&counts[bg * GG + q0 * 128 + q1], 1);
  }
}

__global__ __launch_bounds__(256) void k_s1(const int* __restrict__ counts,
                                            int* __restrict__ blockcnt) {
  __shared__ int red[256];
  int t = threadIdx.x;
  int base = blockIdx.x * 1024 + t * 4;
  int c = 0;
#pragma unroll
  for (int i = 0; i < 4; ++i) c += (counts[base + i] > 0) ? 1 : 0;
  red[t] = c;
  __syncthreads();
  for (int d = 128; d > 0; d >>= 1) {
    if (t < d) red[t] += red[t + d];
    __syncthreads();
  }
  if (t == 0) blockcnt[blockIdx.x] = red[0];
}

__global__ __launch_bounds__(256) void k_s2(const int* __restrict__ blockcnt,
                                            int* __restrict__ blockoff,
                                            int* __restrict__ dM,
                                            int* __restrict__ npts) {
  __shared__ int s[256];
  int t = threadIdx.x;
  int v = blockcnt[t];
  s[t] = v;
  __syncthreads();
  for (int d = 1; d < 256; d <<= 1) {
    int x = (t >= d) ? s[t - d] : 0;
    __syncthreads();
    s[t] += x;
    __syncthreads();
  }
  blockoff[t] = s[t] - v;
  if (t == 255) *dM = s[255];
  if (t < NBAG) {
    int sum = 0;
    for (int i = 0; i < 16; ++i) sum += blockcnt[t * 16 + i];
    npts[t] = sum;
  }
}

__global__ __launch_bounds__(256) void k_s3(const int* __restrict__ counts,
                                            const int* __restrict__ blockoff,
                                            int* __restrict__ cellidx,
                                            int* __restrict__ cell_of_idx) {
  __shared__ int s[256];
  int t = threadIdx.x;
  int base = blockIdx.x * 1024 + t * 4;
  int occ[4];
  int c = 0;
#pragma unroll
  for (int i = 0; i < 4; ++i) {
    occ[i] = counts[base + i] > 0;
    c += occ[i];
  }
  s[t] = c;
  __syncthreads();
  for (int d = 1; d < 256; d <<= 1) {
    int x = (t >= d) ? s[t - d] : 0;
    __syncthreads();
    s[t] += x;
    __syncthreads();
  }
  int pos = blockoff[blockIdx.x] + s[t] - c;
#pragma unroll
  for (int i = 0; i < 4; ++i) {
    if (occ[i]) {
      cellidx[base + i] = pos;
      cell_of_idx[pos] = base + i;
      pos++;
    } else {
      cellidx[base + i] = -1;
    }
  }
}

__global__ __launch_bounds__(256) void k_scatter(const float* __restrict__ x,
                                                 const int* __restrict__ coords,
                                                 const int* __restrict__ cellidx,
                                                 float* __restrict__ fsum) {
  int gid = blockIdx.x * 256 + threadIdx.x;
  int p = gid >> 7, c = gid & 127;
  int b = p >> 12;
  int q0 = coords[p * 2 + 0] >> 5;
  int q1 = coords[p * 2 + 1] >> 5;
  int idx = cellidx[b * GG + q0 * 128 + q1];
  atomicAdd(&fsum[(size_t)idx * 128 + c], x[(size_t)p * 128 + c]);
}

// fused: average+cast (blocks [0,4097)) and neighbor table (blocks [4097,4353))
__global__ __launch_bounds__(256) void k_prep(const float* __restrict__ fsum,
                                              const int* __restrict__ counts,
                                              const int* __restrict__ cell_of_idx,
                                              const int* __restrict__ cellidx,
                                              const int* __restrict__ dM,
                                              __hip_bfloat16* __restrict__ feat0,
                                              __hip_bfloat16* __restrict__ feat1,
                                              int* __restrict__ nbrt) {
  int t = threadIdx.x;
  if (blockIdx.x < 4097) {
    int gid = blockIdx.x * 256 + t;
    int cell = gid >> 4, i = gid & 15;
    int M = *dM;
    if (cell >= M) {
      if (cell == M) {
        *(int4*)((char*)(feat0 + (size_t)ZROW * 128) + i * 16) = make_int4(0, 0, 0, 0);
      } else if (cell == M + 1) {
        *(int4*)((char*)(feat1 + (size_t)ZROW * 128) + i * 16) = make_int4(0, 0, 0, 0);
      }
      return;
    }
    float inv = 1.0f / (float)counts[cell_of_idx[cell]];
    const float4* src = (const float4*)fsum + (size_t)cell * 32 + i * 2;
    float4 v0 = src[0], v1 = src[1];
    __align__(16) __hip_bfloat16 h[8];
    h[0] = __float2bfloat16(v0.x * inv);
    h[1] = __float2bfloat16(v0.y * inv);
    h[2] = __float2bfloat16(v0.z * inv);
    h[3] = __float2bfloat16(v0.w * inv);
    h[4] = __float2bfloat16(v1.x * inv);
    h[5] = __float2bfloat16(v1.y * inv);
    h[6] = __float2bfloat16(v1.z * inv);
    h[7] = __float2bfloat16(v1.w * inv);
    *(int4*)(feat0 + (size_t)cell * 128 + i * 8) = *(const int4*)h;
  } else {
    int idx = (blockIdx.x - 4097) * 256 + t;
    if (idx >= MAXM) return;
    if (idx >= *dM) {
#pragma unroll
      for (int j = 0; j < 9; ++j) nbrt[j * MAXM + idx] = ZROW;
      return;
    }
    int cell = cell_of_idx[idx];
    int b = cell >> 14, ij = cell & 16383;
    int i = ij >> 7, j = ij & 127;
#pragma unroll
    for (int dh = 0; dh < 3; ++dh)
#pragma unroll
      for (int dw = 0; dw < 3; ++dw) {
        int ni = i + dh - 1, nj = j + dw - 1;
        int v = -1;
        if (ni >= 0 && ni < 128 && nj >= 0 && nj < 128)
          v = cellidx[b * GG + ni * 128 + nj];
        nbrt[(dh * 3 + dw) * MAXM + idx] = (v < 0) ? ZROW : v;
      }
  }
}

// MFMA gathered sparse conv.
//   Chunked XCD swizzle: cg-pairs (same A rows) land on one XCD -> L2-resident
//   feat slice (~2MB) + Wt (288KB).
//   A: parity ping-pong regs aP[2][..] (static idx after full unroll, no copy),
//   prefetched 1 tap ahead; nbr indices 2 taps ahead; ZROW kills predication.
//   W: per-tap 16KB pre-swizzled tile via global_load_lds, 2x16KB LDS dbuf.
//   launch_bounds(256,3): ~160 VGPR headroom so both A tap-buffers stay live.
template <bool POOL>
__global__ __launch_bounds__(256, 3) void k_conv(
    const __hip_bfloat16* __restrict__ fin,   // [MAXM+1][128]
    const __hip_bfloat16* __restrict__ Wt,    // [9][128][128] pre-swizzled
    __hip_bfloat16* __restrict__ fout,
    float* __restrict__ pooled,
    const int* __restrict__ nbrt,             // [9][MAXM]
    const int* __restrict__ cell_of_idx,
    const int* __restrict__ dM) {
  __shared__ __align__(16) char smem[32768];
  const int M = *dM;
  // bijective chunked XCD swizzle (gridDim.x = 1024, divisible by 8)
  const int lb = (blockIdx.x & 7) * (gridDim.x >> 3) + (blockIdx.x >> 3);
  const int cg = lb & 1;
  const int base = (lb >> 1) * 128;
  if (base >= M) return;
  const int t = threadIdx.x;
  const int w = t >> 6;
  const int l = t & 63;
  const int u = l >> 4;
  const int c = l & 15;
  const int wrow = base + w * 32;

  auto stageW = [&](int k, int b) {
    const __hip_bfloat16* gw = Wt + (size_t)k * 16384 + cg * 8192 + w * 2048;
    char* lbuf = smem + b * 16384 + w * 4096;
#pragma unroll
    for (int j = 0; j < 4; ++j) {
      __builtin_amdgcn_global_load_lds(
          (const __attribute__((address_space(1))) void*)(gw + j * 512 + l * 8),
          (__attribute__((address_space(3))) void*)(lbuf + j * 1024), 16, 0, 0);
    }
  };
  auto loadA = [&](int nb, int kb) {
    return *(const bf16x8*)((const char*)fin + (size_t)nb * 256 + kb * 64 + u * 16);
  };

  f32x4 acc[2][4];
#pragma unroll
  for (int mf = 0; mf < 2; ++mf)
#pragma unroll
    for (int nf = 0; nf < 4; ++nf) acc[mf][nf] = f32x4{0.f, 0.f, 0.f, 0.f};

  bf16x8 aP[2][2][4];  // [parity][mf][kb]
  int nb_c[2], nb_n[2];
  nb_c[0] = nbrt[0 * MAXM + wrow + c];
  nb_c[1] = nbrt[0 * MAXM + wrow + 16 + c];
  nb_n[0] = nbrt[1 * MAXM + wrow + c];
  nb_n[1] = nbrt[1 * MAXM + wrow + 16 + c];
  stageW(0, 0);
#pragma unroll
  for (int mf = 0; mf < 2; ++mf)
#pragma unroll
    for (int kb = 0; kb < 4; ++kb) aP[0][mf][kb] = loadA(nb_c[mf], kb);
  __syncthreads();  // W(0) in LDS, A(0) in regs

#pragma unroll
  for (int k = 0; k < 9; ++k) {
    const int cp = k & 1, np = cp ^ 1;  // constants after full unroll
    if (k < 8) {
      stageW(k + 1, (k + 1) & 1);
#pragma unroll
      for (int mf = 0; mf < 2; ++mf)
#pragma unroll
        for (int kb = 0; kb < 4; ++kb) aP[np][mf][kb] = loadA(nb_n[mf], kb);
    }
    if (k < 7) {
      nb_n[0] = nbrt[(k + 2) * MAXM + wrow + c];
      nb_n[1] = nbrt[(k + 2) * MAXM + wrow + 16 + c];
    }
    const char* wb = smem + (k & 1) * 16384;
    __builtin_amdgcn_s_setprio(1);
#pragma unroll
    for (int kb = 0; kb < 4; ++kb) {
      bf16x8 wf[4];
#pragma unroll
      for (int nf = 0; nf < 4; ++nf) {
        int co = nf * 16 + c;
        int ch = (kb * 4 + u) ^ (c & 7);
        wf[nf] = *(const bf16x8*)(wb + co * 256 + ch * 16);
      }
#pragma unroll
      for (int mf = 0; mf < 2; ++mf)
#pragma unroll
        for (int nf = 0; nf < 4; ++nf)
          acc[mf][nf] = __builtin_amdgcn_mfma_f32_16x16x32_bf16(
              aP[cp][mf][kb], wf[nf], acc[mf][nf], 0, 0, 0);
    }
    __builtin_amdgcn_s_setprio(0);
    __syncthreads();  // protects LDS dbuf flip (drains W(k+1) + A(k+1))
  }

  if (!POOL) {
    char* ep = smem + w * 4608;  // per-wave region, stride 144 breaks conflicts
#pragma unroll
    for (int mf = 0; mf < 2; ++mf)
#pragma unroll
      for (int nf = 0; nf < 4; ++nf)
#pragma unroll
        for (int i = 0; i < 4; ++i) {
          int rl = mf * 16 + u * 4 + i;
          int col = nf * 16 + c;
          *(__hip_bfloat16*)(ep + rl * 144 + col * 2) =
              __float2bfloat16(fmaxf(acc[mf][nf][i], 0.f));
        }
    __syncthreads();
#pragma unroll
    for (int p = 0; p < 4; ++p) {
      int rl = p * 8 + (l >> 3);
      int grow = wrow + rl;
      int4 v = *(const int4*)(ep + rl * 144 + (l & 7) * 16);
      if (grow < M)
        *(int4*)((char*)fout + (size_t)grow * 256 + cg * 128 + (l & 7) * 16) = v;
    }
  } else {
    if (wrow < M) {
      int b0 = cell_of_idx[wrow] >> 14;
      int lastr = min(wrow + 31, M - 1);
      int b1 = cell_of_idx[lastr] >> 14;
      float p0[4] = {0.f, 0.f, 0.f, 0.f}, p1[4] = {0.f, 0.f, 0.f, 0.f};
#pragma unroll
      for (int mf = 0; mf < 2; ++mf)
#pragma unroll
        for (int i = 0; i < 4; ++i) {
          int r = wrow + mf * 16 + u * 4 + i;
          int bg = (r < M) ? (cell_of_idx[r] >> 14) : -1;
#pragma unroll
          for (int nf = 0; nf < 4; ++nf) {
            float v = fmaxf(acc[mf][nf][i], 0.f);
            if (bg == b0) p0[nf] += v;
            else if (bg == b1) p1[nf] += v;
          }
        }
      bool two = (b1 != b0);
#pragma unroll
      for (int nf = 0; nf < 4; ++nf) {
        p0[nf] += __shfl_xor(p0[nf], 16);
        p0[nf] += __shfl_xor(p0[nf], 32);
        p1[nf] += __shfl_xor(p1[nf], 16);
        p1[nf] += __shfl_xor(p1[nf], 32);
      }
      if (u == 0) {
#pragma unroll
        for (int nf = 0; nf < 4; ++nf) {
          atomicAdd(&pooled[b0 * 128 + cg * 64 + nf * 16 + c], p0[nf]);
          if (two) atomicAdd(&pooled[b1 * 128 + cg * 64 + nf * 16 + c], p1[nf]);
        }
      }
    }
  }
}

__global__ __launch_bounds__(256) void k_logits(const float* __restrict__ pooled,
                                                const int* __restrict__ npts,
                                                const float* __restrict__ Wc,
                                                const float* __restrict__ bc,
                                                float* __restrict__ out) {
  int t = threadIdx.x;
  if (t >= 160) return;
  int b = t / 10, n = t % 10;
  float inv = 1.0f / (float)npts[b];
  float s = 0.f;
  for (int c = 0; c < 128; ++c) s += pooled[b * 128 + c] * Wc[c * 10 + n];
  out[t] = s * inv + bc[n];
}

extern "C" void kernel_launch(void* const* d_in, const int* in_sizes, int n_in,
                              void* d_out, int out_size, void* d_ws, size_t ws_size,
                              hipStream_t stream) {
  const float* x = (const float*)d_in[0];
  const int* coords = (const int*)d_in[1];
  const float* W1 = (const float*)d_in[2];
  const float* W2 = (const float*)d_in[3];
  const float* Wc = (const float*)d_in[4];
  const float* bc = (const float*)d_in[5];
  float* out = (float*)d_out;

  char* ws = (char*)d_ws;
  size_t off = 0;
  auto take = [&](size_t bytes) {
    void* p = ws + off;
    off += (bytes + 255) & ~(size_t)255;
    return p;
  };
  int* counts      = (int*)take((size_t)NCELL * 4);
  int* cellidx     = (int*)take((size_t)NCELL * 4);
  int* cell_of_idx = (int*)take((size_t)MAXM * 4);
  int* blockcnt    = (int*)take(256 * 4);
  int* blockoff    = (int*)take(256 * 4);
  int* dM          = (int*)take(4);
  int* npts        = (int*)take(64);
  int* nbrt        = (int*)take((size_t)9 * MAXM * 4);
  float* fsum      = (float*)take((size_t)MAXM * 128 * 4);
  __hip_bfloat16* feat0 = (__hip_bfloat16*)take((size_t)(MAXM + 1) * 128 * 2);
  __hip_bfloat16* feat1 = (__hip_bfloat16*)take((size_t)(MAXM + 1) * 128 * 2);
  __hip_bfloat16* Wt1   = (__hip_bfloat16*)take((size_t)9 * 128 * 128 * 2);
  __hip_bfloat16* Wt2   = (__hip_bfloat16*)take((size_t)9 * 128 * 128 * 2);
  float* pooled    = (float*)take(16 * 128 * 4);

  k_zero<<<2048, 256, 0, stream>>>(fsum, counts, pooled);
  k_setup<<<1408, 256, 0, stream>>>(W1, W2, Wt1, Wt2, coords, counts);
  k_s1<<<256, 256, 0, stream>>>(counts, blockcnt);
  k_s2<<<1, 256, 0, stream>>>(blockcnt, blockoff, dM, npts);
  k_s3<<<256, 256, 0, stream>>>(counts, blockoff, cellidx, cell_of_idx);
  k_scatter<<<NPT * 128 / 256, 256, 0, stream>>>(x, coords, cellidx, fsum);
  k_prep<<<4353, 256, 0, stream>>>(fsum, counts, cell_of_idx, cellidx, dM, feat0, feat1, nbrt);
  k_conv<false><<<(MAXM / 128) * 2, 256, 0, stream>>>(feat0, Wt1, feat1, nullptr, nbrt, cell_of_idx, dM);
  k_conv<true><<<(MAXM / 128) * 2, 256, 0, stream>>>(feat1, Wt2, nullptr, pooled, nbrt, cell_of_idx, dM);
  k_logits<<<1, 256, 0, stream>>>(pooled, npts, Wc, bc, out);
}

// Round 5
// 108.470 us; speedup vs baseline: 5.9910x; 1.2357x over previous
//
#include <hip/hip_runtime.h>
#include <hip/hip_bf16.h>

#define GG 16384          // G*G
#define NBAG 16
#define NPT 65536
#define NCELL (NBAG * GG)
#define MAXM NPT
#define ZROW MAXM         // dedicated zero row in feat buffers (sized MAXM+1 rows)

typedef __bf16 bf16x8 __attribute__((ext_vector_type(8)));
typedef float f32x4 __attribute__((ext_vector_type(4)));

// fused zero: counts (1MB) + fsum (32MB) + pooled (8KB), one launch, int4 stores
__global__ __launch_bounds__(256) void k_zero(float* __restrict__ fsum,
                                              int* __restrict__ counts,
                                              float* __restrict__ pooled) {
  int tid = blockIdx.x * 256 + threadIdx.x;  // grid 2048*256 = 524288
  int4 z = make_int4(0, 0, 0, 0);
#pragma unroll
  for (int i = 0; i < 4; ++i) ((int4*)fsum)[tid + i * 524288] = z;
  if (tid < 65536) ((int4*)counts)[tid] = z;
  if (tid < 512) ((int4*)pooled)[tid] = z;
}

// fused: weight transpose+cast+pre-swizzle (blocks [0,1152)) and point count
__global__ __launch_bounds__(256) void k_setup(const float* __restrict__ W1,
                                               const float* __restrict__ W2,
                                               __hip_bfloat16* __restrict__ Wt1,
                                               __hip_bfloat16* __restrict__ Wt2,
                                               const int* __restrict__ coords,
                                               int* __restrict__ counts) {
  int b = blockIdx.x, t = threadIdx.x;
  if (b < 1152) {
    int id = b * 256 + t;  // < 2*147456
    const float* W = (id < 147456) ? W1 : W2;
    __hip_bfloat16* Wt = (id < 147456) ? Wt1 : Wt2;
    int r = (id < 147456) ? id : id - 147456;
    int k = r >> 14, rem = r & 16383, co = rem >> 7, ci = rem & 127;
    int dst = k * 16384 + co * 128 + (((ci >> 3) ^ (co & 7)) << 3) + (ci & 7);
    Wt[dst] = __float2bfloat16(W[k * 16384 + ci * 128 + co]);
  } else {
    int p = (b - 1152) * 256 + t;
    int bg = p >> 12;
    int q0 = coords[p * 2 + 0] >> 5;
    int q1 = coords[p * 2 + 1] >> 5;
    atomicAdd(&counts[bg * GG + q0 * 128 + q1], 1);
  }
}

__global__ __launch_bounds__(256) void k_s1(const int* __restrict__ counts,
                                            int* __restrict__ blockcnt) {
  __shared__ int red[256];
  int t = threadIdx.x;
  int base = blockIdx.x * 1024 + t * 4;
  int c = 0;
#pragma unroll
  for (int i = 0; i < 4; ++i) c += (counts[base + i] > 0) ? 1 : 0;
  red[t] = c;
  __syncthreads();
  for (int d = 128; d > 0; d >>= 1) {
    if (t < d) red[t] += red[t + d];
    __syncthreads();
  }
  if (t == 0) blockcnt[blockIdx.x] = red[0];
}

__global__ __launch_bounds__(256) void k_s2(const int* __restrict__ blockcnt,
                                            int* __restrict__ blockoff,
                                            int* __restrict__ dM,
                                            int* __restrict__ npts) {
  __shared__ int s[256];
  int t = threadIdx.x;
  int v = blockcnt[t];
  s[t] = v;
  __syncthreads();
  for (int d = 1; d < 256; d <<= 1) {
    int x = (t >= d) ? s[t - d] : 0;
    __syncthreads();
    s[t] += x;
    __syncthreads();
  }
  blockoff[t] = s[t] - v;
  if (t == 255) *dM = s[255];
  if (t < NBAG) {
    int sum = 0;
    for (int i = 0; i < 16; ++i) sum += blockcnt[t * 16 + i];
    npts[t] = sum;
  }
}

__global__ __launch_bounds__(256) void k_s3(const int* __restrict__ counts,
                                            const int* __restrict__ blockoff,
                                            int* __restrict__ cellidx,
                                            int* __restrict__ cell_of_idx) {
  __shared__ int s[256];
  int t = threadIdx.x;
  int base = blockIdx.x * 1024 + t * 4;
  int occ[4];
  int c = 0;
#pragma unroll
  for (int i = 0; i < 4; ++i) {
    occ[i] = counts[base + i] > 0;
    c += occ[i];
  }
  s[t] = c;
  __syncthreads();
  for (int d = 1; d < 256; d <<= 1) {
    int x = (t >= d) ? s[t - d] : 0;
    __syncthreads();
    s[t] += x;
    __syncthreads();
  }
  int pos = blockoff[blockIdx.x] + s[t] - c;
#pragma unroll
  for (int i = 0; i < 4; ++i) {
    if (occ[i]) {
      cellidx[base + i] = pos;
      cell_of_idx[pos] = base + i;
      pos++;
    } else {
      cellidx[base + i] = -1;
    }
  }
}

// scatter: count==1 cells (≈88%) write bf16 feat0 directly; else atomic fsum
__global__ __launch_bounds__(256) void k_scatter(const float* __restrict__ x,
                                                 const int* __restrict__ coords,
                                                 const int* __restrict__ cellidx,
                                                 const int* __restrict__ counts,
                                                 float* __restrict__ fsum,
                                                 __hip_bfloat16* __restrict__ feat0) {
  int gid = blockIdx.x * 256 + threadIdx.x;
  int p = gid >> 7, c = gid & 127;
  int b = p >> 12;
  int q0 = coords[p * 2 + 0] >> 5;
  int q1 = coords[p * 2 + 1] >> 5;
  int cell = b * GG + q0 * 128 + q1;
  int idx = cellidx[cell];
  float v = x[(size_t)p * 128 + c];
  if (counts[cell] == 1) {
    feat0[(size_t)idx * 128 + c] = __float2bfloat16(v);
  } else {
    atomicAdd(&fsum[(size_t)idx * 128 + c], v);
  }
}

// fused: average+cast for count>1 cells (blocks [0,4097)) and nbr table
__global__ __launch_bounds__(256) void k_prep(const float* __restrict__ fsum,
                                              const int* __restrict__ counts,
                                              const int* __restrict__ cell_of_idx,
                                              const int* __restrict__ cellidx,
                                              const int* __restrict__ dM,
                                              __hip_bfloat16* __restrict__ feat0,
                                              __hip_bfloat16* __restrict__ feat1,
                                              int* __restrict__ nbrt) {
  int t = threadIdx.x;
  if (blockIdx.x < 4097) {
    int gid = blockIdx.x * 256 + t;
    int cell = gid >> 4, i = gid & 15;
    int M = *dM;
    if (cell >= M) {
      if (cell == M) {
        *(int4*)((char*)(feat0 + (size_t)ZROW * 128) + i * 16) = make_int4(0, 0, 0, 0);
      } else if (cell == M + 1) {
        *(int4*)((char*)(feat1 + (size_t)ZROW * 128) + i * 16) = make_int4(0, 0, 0, 0);
      }
      return;
    }
    int cnt = counts[cell_of_idx[cell]];
    if (cnt == 1) return;  // already written by k_scatter
    float inv = 1.0f / (float)cnt;
    const float4* src = (const float4*)fsum + (size_t)cell * 32 + i * 2;
    float4 v0 = src[0], v1 = src[1];
    __align__(16) __hip_bfloat16 h[8];
    h[0] = __float2bfloat16(v0.x * inv);
    h[1] = __float2bfloat16(v0.y * inv);
    h[2] = __float2bfloat16(v0.z * inv);
    h[3] = __float2bfloat16(v0.w * inv);
    h[4] = __float2bfloat16(v1.x * inv);
    h[5] = __float2bfloat16(v1.y * inv);
    h[6] = __float2bfloat16(v1.z * inv);
    h[7] = __float2bfloat16(v1.w * inv);
    *(int4*)(feat0 + (size_t)cell * 128 + i * 8) = *(const int4*)h;
  } else {
    int idx = (blockIdx.x - 4097) * 256 + t;
    if (idx >= MAXM) return;
    if (idx >= *dM) {
#pragma unroll
      for (int j = 0; j < 9; ++j) nbrt[j * MAXM + idx] = ZROW;
      return;
    }
    int cell = cell_of_idx[idx];
    int b = cell >> 14, ij = cell & 16383;
    int i = ij >> 7, j = ij & 127;
#pragma unroll
    for (int dh = 0; dh < 3; ++dh)
#pragma unroll
      for (int dw = 0; dw < 3; ++dw) {
        int ni = i + dh - 1, nj = j + dw - 1;
        int v = -1;
        if (ni >= 0 && ni < 128 && nj >= 0 && nj < 128)
          v = cellidx[b * GG + ni * 128 + nj];
        nbrt[(dh * 3 + dw) * MAXM + idx] = (v < 0) ? ZROW : v;
      }
  }
}

// MFMA gathered sparse conv v3: block = 128 rows x ALL 128 couts, 4 waves.
//   Wave w: rows [base+w*32,+32) x 128 couts -> 64 MFMAs/tap/wave (2x R4),
//   so 2 resident blocks/CU give ~620cy MFMA per SIMD per tap — covers the
//   ~600cy gather latency. Each A-row gathered once (no cg duplication).
//   A: parity ping-pong regs, 1 tap ahead; nbr 2 taps ahead; ZROW = zero row.
//   W: 32KB/tap pre-swizzled tile via global_load_lds, 2x32KB LDS dbuf.
template <bool POOL>
__global__ __launch_bounds__(256, 2) void k_conv(
    const __hip_bfloat16* __restrict__ fin,   // [MAXM+1][128]
    const __hip_bfloat16* __restrict__ Wt,    // [9][128][128] pre-swizzled
    __hip_bfloat16* __restrict__ fout,
    float* __restrict__ pooled,
    const int* __restrict__ nbrt,             // [9][MAXM]
    const int* __restrict__ cell_of_idx,
    const int* __restrict__ dM) {
  __shared__ __align__(16) char smem[65536];
  const int M = *dM;
  // bijective chunked XCD swizzle (gridDim.x = 512, divisible by 8)
  const int lb = (blockIdx.x & 7) * (gridDim.x >> 3) + (blockIdx.x >> 3);
  const int base = lb * 128;
  if (base >= M) return;
  const int t = threadIdx.x;
  const int w = t >> 6;
  const int l = t & 63;
  const int u = l >> 4;
  const int c = l & 15;
  const int wrow = base + w * 32;

  auto stageW = [&](int k, int b) {
    const __hip_bfloat16* gw = Wt + (size_t)k * 16384 + w * 4096;
    char* lbuf = smem + b * 32768 + w * 8192;
#pragma unroll
    for (int j = 0; j < 8; ++j) {
      __builtin_amdgcn_global_load_lds(
          (const __attribute__((address_space(1))) void*)(gw + j * 512 + l * 8),
          (__attribute__((address_space(3))) void*)(lbuf + j * 1024), 16, 0, 0);
    }
  };
  auto loadA = [&](int nb, int kb) {
    return *(const bf16x8*)((const char*)fin + (size_t)nb * 256 + kb * 64 + u * 16);
  };

  f32x4 acc[2][8];
#pragma unroll
  for (int mf = 0; mf < 2; ++mf)
#pragma unroll
    for (int nf = 0; nf < 8; ++nf) acc[mf][nf] = f32x4{0.f, 0.f, 0.f, 0.f};

  bf16x8 aP[2][2][4];  // [parity][mf][kb]
  int nb_c[2], nb_n[2];
  nb_c[0] = nbrt[0 * MAXM + wrow + c];
  nb_c[1] = nbrt[0 * MAXM + wrow + 16 + c];
  nb_n[0] = nbrt[1 * MAXM + wrow + c];
  nb_n[1] = nbrt[1 * MAXM + wrow + 16 + c];
#pragma unroll
  for (int mf = 0; mf < 2; ++mf)
#pragma unroll
    for (int kb = 0; kb < 4; ++kb) aP[0][mf][kb] = loadA(nb_c[mf], kb);
  stageW(0, 0);
  __syncthreads();  // W(0) in LDS, A(0) in regs

#pragma unroll
  for (int k = 0; k < 9; ++k) {
    const int cp = k & 1, np = cp ^ 1;  // constants after full unroll
    if (k < 8) {
#pragma unroll
      for (int mf = 0; mf < 2; ++mf)
#pragma unroll
        for (int kb = 0; kb < 4; ++kb) aP[np][mf][kb] = loadA(nb_n[mf], kb);
      stageW(k + 1, (k + 1) & 1);
    }
    if (k < 7) {
      nb_n[0] = nbrt[(k + 2) * MAXM + wrow + c];
      nb_n[1] = nbrt[(k + 2) * MAXM + wrow + 16 + c];
    }
    const char* wb = smem + (k & 1) * 32768;
    __builtin_amdgcn_s_setprio(1);
#pragma unroll
    for (int kb = 0; kb < 4; ++kb) {
      bf16x8 wf[8];
#pragma unroll
      for (int nf = 0; nf < 8; ++nf) {
        int co = nf * 16 + c;
        int ch = (kb * 4 + u) ^ (c & 7);
        wf[nf] = *(const bf16x8*)(wb + co * 256 + ch * 16);
      }
#pragma unroll
      for (int mf = 0; mf < 2; ++mf)
#pragma unroll
        for (int nf = 0; nf < 8; ++nf)
          acc[mf][nf] = __builtin_amdgcn_mfma_f32_16x16x32_bf16(
              aP[cp][mf][kb], wf[nf], acc[mf][nf], 0, 0, 0);
    }
    __builtin_amdgcn_s_setprio(0);
    __syncthreads();  // protects LDS dbuf flip
  }

  if (!POOL) {
    char* ep = smem + w * 8704;  // 32 rows x 272B (16B pad breaks conflicts)
#pragma unroll
    for (int mf = 0; mf < 2; ++mf)
#pragma unroll
      for (int nf = 0; nf < 8; ++nf)
#pragma unroll
        for (int i = 0; i < 4; ++i) {
          int rl = mf * 16 + u * 4 + i;
          int col = nf * 16 + c;
          *(__hip_bfloat16*)(ep + rl * 272 + col * 2) =
              __float2bfloat16(fmaxf(acc[mf][nf][i], 0.f));
        }
    __syncthreads();
#pragma unroll
    for (int j = 0; j < 8; ++j) {
      int rl = j * 4 + u;
      int grow = wrow + rl;
      int4 v = *(const int4*)(ep + rl * 272 + c * 16);
      if (grow < M)
        *(int4*)((char*)fout + (size_t)grow * 256 + c * 16) = v;
    }
  } else {
    if (wrow < M) {
      int b0 = cell_of_idx[wrow] >> 14;
      int lastr = min(wrow + 31, M - 1);
      int b1 = cell_of_idx[lastr] >> 14;
      float p0[8] = {0.f, 0.f, 0.f, 0.f, 0.f, 0.f, 0.f, 0.f};
      float p1[8] = {0.f, 0.f, 0.f, 0.f, 0.f, 0.f, 0.f, 0.f};
#pragma unroll
      for (int mf = 0; mf < 2; ++mf)
#pragma unroll
        for (int i = 0; i < 4; ++i) {
          int r = wrow + mf * 16 + u * 4 + i;
          int bg = (r < M) ? (cell_of_idx[r] >> 14) : -1;
#pragma unroll
          for (int nf = 0; nf < 8; ++nf) {
            float v = fmaxf(acc[mf][nf][i], 0.f);
            if (bg == b0) p0[nf] += v;
            else if (bg == b1) p1[nf] += v;
          }
        }
      bool two = (b1 != b0);
#pragma unroll
      for (int nf = 0; nf < 8; ++nf) {
        p0[nf] += __shfl_xor(p0[nf], 16);
        p0[nf] += __shfl_xor(p0[nf], 32);
        p1[nf] += __shfl_xor(p1[nf], 16);
        p1[nf] += __shfl_xor(p1[nf], 32);
      }
      if (u == 0) {
#pragma unroll
        for (int nf = 0; nf < 8; ++nf) {
          atomicAdd(&pooled[b0 * 128 + nf * 16 + c], p0[nf]);
          if (two) atomicAdd(&pooled[b1 * 128 + nf * 16 + c], p1[nf]);
        }
      }
    }
  }
}

__global__ __launch_bounds__(256) void k_logits(const float* __restrict__ pooled,
                                                const int* __restrict__ npts,
                                                const float* __restrict__ Wc,
                                                const float* __restrict__ bc,
                                                float* __restrict__ out) {
  int t = threadIdx.x;
  if (t >= 160) return;
  int b = t / 10, n = t % 10;
  float inv = 1.0f / (float)npts[b];
  float s = 0.f;
  for (int c = 0; c < 128; ++c) s += pooled[b * 128 + c] * Wc[c * 10 + n];
  out[t] = s * inv + bc[n];
}

extern "C" void kernel_launch(void* const* d_in, const int* in_sizes, int n_in,
                              void* d_out, int out_size, void* d_ws, size_t ws_size,
                              hipStream_t stream) {
  const float* x = (const float*)d_in[0];
  const int* coords = (const int*)d_in[1];
  const float* W1 = (const float*)d_in[2];
  const float* W2 = (const float*)d_in[3];
  const float* Wc = (const float*)d_in[4];
  const float* bc = (const float*)d_in[5];
  float* out = (float*)d_out;

  char* ws = (char*)d_ws;
  size_t off = 0;
  auto take = [&](size_t bytes) {
    void* p = ws + off;
    off += (bytes + 255) & ~(size_t)255;
    return p;
  };
  int* counts      = (int*)take((size_t)NCELL * 4);
  int* cellidx     = (int*)take((size_t)NCELL * 4);
  int* cell_of_idx = (int*)take((size_t)MAXM * 4);
  int* blockcnt    = (int*)take(256 * 4);
  int* blockoff    = (int*)take(256 * 4);
  int* dM          = (int*)take(4);
  int* npts        = (int*)take(64);
  int* nbrt        = (int*)take((size_t)9 * MAXM * 4);
  float* fsum      = (float*)take((size_t)MAXM * 128 * 4);
  __hip_bfloat16* feat0 = (__hip_bfloat16*)take((size_t)(MAXM + 1) * 128 * 2);
  __hip_bfloat16* feat1 = (__hip_bfloat16*)take((size_t)(MAXM + 1) * 128 * 2);
  __hip_bfloat16* Wt1   = (__hip_bfloat16*)take((size_t)9 * 128 * 128 * 2);
  __hip_bfloat16* Wt2   = (__hip_bfloat16*)take((size_t)9 * 128 * 128 * 2);
  float* pooled    = (float*)take(16 * 128 * 4);

  k_zero<<<2048, 256, 0, stream>>>(fsum, counts, pooled);
  k_setup<<<1408, 256, 0, stream>>>(W1, W2, Wt1, Wt2, coords, counts);
  k_s1<<<256, 256, 0, stream>>>(counts, blockcnt);
  k_s2<<<1, 256, 0, stream>>>(blockcnt, blockoff, dM, npts);
  k_s3<<<256, 256, 0, stream>>>(counts, blockoff, cellidx, cell_of_idx);
  k_scatter<<<NPT * 128 / 256, 256, 0, stream>>>(x, coords, cellidx, counts, fsum, feat0);
  k_prep<<<4353, 256, 0, stream>>>(fsum, counts, cell_of_idx, cellidx, dM, feat0, feat1, nbrt);
  k_conv<false><<<MAXM / 128, 256, 0, stream>>>(feat0, Wt1, feat1, nullptr, nbrt, cell_of_idx, dM);
  k_conv<true><<<MAXM / 128, 256, 0, stream>>>(feat1, Wt2, nullptr, pooled, nbrt, cell_of_idx, dM);
  k_logits<<<1, 256, 0, stream>>>(pooled, npts, Wc, bc, out);
}